// Round 7
// baseline (524.662 us; speedup 1.0000x reference)
//
#include <hip/hip_runtime.h>
#include <stdint.h>

// R7: 8-phase 256x256 GEMM (m201 template, linear LDS; swizzle deferred).

#define DEV __device__ __forceinline__

typedef __attribute__((ext_vector_type(8))) short short8;
typedef __attribute__((ext_vector_type(4))) float floatx4;

// problem dims
#define BATCH 128
#define TT    197
#define DD    768
#define NH    12
#define NROWS (BATCH*TT)   // 25216 = 197*128
#define G4H   3072         // 4*H rows of gate weights
#define MT8   99           // m-tiles of 256 (last half-valid)
#define NT8   3            // n-tiles of 256

DEV uint16_t f2bf(float f) {
    union { float f; uint32_t u; } v; v.f = f;
    uint32_t r = (v.u + 0x7FFF + ((v.u >> 16) & 1)) >> 16;  // RNE
    return (uint16_t)r;
}

DEV floatx4 mfma16(short8 a, short8 b, floatx4 c) {
    return __builtin_amdgcn_mfma_f32_16x16x32_bf16(a, b, c, 0, 0, 0);
}

DEV float sigf(float x)   { return __builtin_amdgcn_rcpf(1.0f + __expf(-x)); }
DEV float tanhf_(float x) { return 1.0f - 2.0f * __builtin_amdgcn_rcpf(1.0f + __expf(2.0f * x)); }

// async global->LDS, 16B per lane; lds base must be wave-uniform (HW adds lane*16)
DEV void async16(const uint16_t* g, uint16_t* l) {
    __builtin_amdgcn_global_load_lds(
        (const __attribute__((address_space(1))) unsigned int*)g,
        (__attribute__((address_space(3))) unsigned int*)l,
        16, 0, 0);
}

#define CFENCE() asm volatile("" ::: "memory")
// s_waitcnt simm16 encoding (gfx9): vmcnt[3:0]|expcnt[6:4]|lgkmcnt[11:8]|vmcnt[5:4]@[15:14]
#define WAITCNT_LGKM0_ONLY 0xC07F   // lgkmcnt(0), vmcnt/expcnt = no-wait
#define WAITCNT_VM4        0x0F74   // vmcnt(4),   lgkm/expcnt  = no-wait
#define WAITCNT_VM0        0x0F70   // vmcnt(0),   lgkm/expcnt  = no-wait

// ---------------- fused fp32 -> bf16 conversion (all tensors, one launch) ----
struct CvtArgs {
    const float* src[7];
    uint16_t*    dst[7];
    int          n4[7];    // element count / 4
    int          nseg;
};

__global__ void cvt_multi(CvtArgs a) {
    int tid = blockIdx.x * blockDim.x + threadIdx.x;
    int stride = gridDim.x * blockDim.x;
    for (int s = 0; s < a.nseg; s++) {
        const float4* src = (const float4*)a.src[s];
        ushort4* dst = (ushort4*)a.dst[s];
        int n4 = a.n4[s];
        for (int i = tid; i < n4; i += stride) {
            float4 v = src[i];
            ushort4 o;
            o.x = f2bf(v.x); o.y = f2bf(v.y); o.z = f2bf(v.z); o.w = f2bf(v.w);
            dst[i] = o;
        }
    }
}

// ---------------- 8-phase 256x256 bf16 MFMA GEMM: C = A[M,K] @ Bw[N,K]^T + b --
// R0-R6 exhausted the 128-tile/2-barrier family at 129-148 us (460 TF, every
// pipe <30% busy, invariant to sync/occupancy experiments). This is the m201
// 8-phase structure (proven 1167 TF even WITHOUT LDS swizzle, m198), linear
// LDS, adapted to symmetric K-major operands (A [M][K], Bw [N][K]):
//   512 thr = 8 waves (2M x 4N), per-wave output 128x64, BK=64.
//   LDS 128 KB: A,B each [2 dbuf][256 rows][64 k] bf16, staged as 2 half-tiles
//   (128 rows) of 2 x global_load_lds(16B)/thread.
// Per K-tile tt (buf = tt&1), 4 phases, each {ds_read | stage | bar | MFMA | bar}:
//   P1: read A(qm0,8) + B(qn0,4); stage (tt+1).A-half0   -> mfma quad(0,0)
//   P2: read B(qn1,4)           ; stage (tt+1).A-half1   -> quad(0,1)
//   P3: read A(qm1,8)           ; stage (tt+2).B-half0   -> quad(1,0)
//   P4:                           stage (tt+2).B-half1 + VMCNT(4) -> quad(1,1)
// Read-safety (derived, all verified): a stage issues >=1 barrier after its
// region's last reader (A halves last read P3, freed for P1/P2 of NEXT tt via
// opposite buf; B halves last read P2, restaged P3/P4 same buf).
// vmcnt(4)@P4: retires everything through (tt+1).A1 -> tile tt+1 fully landed
// before its P1 reads (2 loads/phase/wave, exactly 4 younger remain). Dead
// tail stages (kt>=NKT) clamp k0=0, keeping counts exact. Prologue stages
// t0{B0,B1,A0,A1}+t1{B0,B1} then vmcnt(4). setprio(1) wraps MFMA (T5, +21% on
// this structure). Bijective XCD swizzle (m204) for nwg=297.
// Boundary: M=25216 = 98.5 tiles; tile 98 half1 rows clamped, stores guarded.
#define PH_BAR() do { CFENCE(); __builtin_amdgcn_s_barrier(); CFENCE(); } while(0)

#define MFMA_QUAD(QM, QN) do { \
    __builtin_amdgcn_s_setprio(1); \
    _Pragma("unroll") \
    for (int ii = 0; ii < 4; ii++) \
        _Pragma("unroll") \
        for (int j = 0; j < 2; j++) { \
            acc[(QM)*4+ii][(QN)*2+j] = mfma16(af[ii][0], bfr[QN][j][0], acc[(QM)*4+ii][(QN)*2+j]); \
            acc[(QM)*4+ii][(QN)*2+j] = mfma16(af[ii][1], bfr[QN][j][1], acc[(QM)*4+ii][(QN)*2+j]); \
        } \
    __builtin_amdgcn_s_setprio(0); \
} while(0)

template<int STORE_BF16, int LAYOUT>
__global__ __launch_bounds__(512, 2) void gemm256q(
    const uint16_t* __restrict__ A,    // [M][K] bf16
    const uint16_t* __restrict__ Bw,   // [N][K] bf16 (weight; transposed use)
    const float*    __restrict__ bias, // [N] fp32
    void*           __restrict__ C,
    int K, int Ntot)
{
    __shared__ __attribute__((aligned(16))) uint16_t lds[65536]; // A:[0,32K) B:[32K,64K) elems

    // bijective XCD swizzle (m204): nwg = 297 (not /8-divisible)
    const int nwg = gridDim.x;
    const int qq = nwg >> 3, rr = nwg & 7;
    const int xcd = blockIdx.x & 7, loc = blockIdx.x >> 3;
    const int swz = (xcd < rr ? xcd*(qq+1) : rr*(qq+1) + (xcd-rr)*qq) + loc;
    const int mt_ = swz / NT8, nt_ = swz - mt_*NT8;
    const int m0 = mt_*256, n0 = nt_*256;

    const int tid  = threadIdx.x;
    const int wv   = tid >> 6;        // 0..7
    const int lane = tid & 63;
    const int ln   = lane & 15;
    const int q    = lane >> 4;
    const int wm   = wv >> 2;         // 0..1: wave M-half
    const int wnx  = wv & 3;          // 0..3: wave N-quarter
    const int NKT  = K >> 6;          // K-tiles (12 or 24)

    floatx4 acc[8][4];
#pragma unroll
    for (int i = 0; i < 8; i++)
#pragma unroll
        for (int j = 0; j < 4; j++) acc[i][j] = (floatx4){0.f, 0.f, 0.f, 0.f};

    // staging source offsets: chunk c = wv*2+l covers rows [c*8, c*8+8) of a
    // 128-row half; lane: row c*8+(lane>>3), k (lane&7)*8.
    const int c0   = wv * 2;
    const int rsub = lane >> 3;
    const int kq8  = (lane & 7) * 8;
    uint32_t gA[2][2], gB[2][2];      // [half][l] element offsets
#pragma unroll
    for (int h = 0; h < 2; h++)
#pragma unroll
        for (int l = 0; l < 2; l++) {
            int row = m0 + h*128 + (c0 + l)*8 + rsub;
            if (row >= NROWS) row = NROWS - 1;   // boundary tile half1 clamp
            gA[h][l] = (uint32_t)row * (uint32_t)K + kq8;
            gB[h][l] = (uint32_t)(n0 + h*128 + (c0 + l)*8 + rsub) * (uint32_t)K + kq8;
        }

    // fragment read bases (LDS row-major [256][64] per buf; halves contiguous)
    const int aL = (wm*128 + ln)*64 + q*8;            // + buf*16384 + i*1024 + s*32
    const int bL = 32768 + wnx*4096 + ln*64 + q*8;    // + buf*16384 + jj*1024 + s*32

    auto stA = [&](int kt, int h) {
        uint32_t k0 = (kt < NKT) ? (uint32_t)(kt << 6) : 0u;  // dead stage clamp
        uint16_t* d = &lds[(kt & 1)*16384 + h*8192 + c0*512];
        async16(A + gA[h][0] + k0, d);
        async16(A + gA[h][1] + k0, d + 512);
    };
    auto stB = [&](int kt, int h) {
        uint32_t k0 = (kt < NKT) ? (uint32_t)(kt << 6) : 0u;
        uint16_t* d = &lds[32768 + (kt & 1)*16384 + h*8192 + c0*512];
        async16(Bw + gB[h][0] + k0, d);
        async16(Bw + gB[h][1] + k0, d + 512);
    };

    // prologue: tile0 full + tile1 B-halves (12 loads/wave); t0 landed gate
    stB(0,0); stB(0,1); stA(0,0); stA(0,1); stB(1,0); stB(1,1);
    CFENCE();
    __builtin_amdgcn_s_waitcnt(WAITCNT_VM4);
    __builtin_amdgcn_s_barrier();
    CFENCE();

    short8 af[4][2];        // A-frags of current qm
    short8 bfr[2][2][2];    // [qn][j][s], both qn sets live across P1..P4

    for (int tt = 0; tt < NKT; tt++) {
        const int lb = (tt & 1) * 16384;
        // ---- P1: A(qm0) + B(qn0) reads; stage (tt+1).A0
#pragma unroll
        for (int ii = 0; ii < 4; ii++) {
            af[ii][0] = *(const short8*)&lds[lb + aL + ii*1024];
            af[ii][1] = *(const short8*)&lds[lb + aL + ii*1024 + 32];
        }
#pragma unroll
        for (int j = 0; j < 2; j++) {
            bfr[0][j][0] = *(const short8*)&lds[lb + bL + j*1024];
            bfr[0][j][1] = *(const short8*)&lds[lb + bL + j*1024 + 32];
        }
        stA(tt + 1, 0);
        PH_BAR();
        MFMA_QUAD(0, 0);
        PH_BAR();
        // ---- P2: B(qn1) reads; stage (tt+1).A1
#pragma unroll
        for (int j = 0; j < 2; j++) {
            bfr[1][j][0] = *(const short8*)&lds[lb + bL + (2+j)*1024];
            bfr[1][j][1] = *(const short8*)&lds[lb + bL + (2+j)*1024 + 32];
        }
        stA(tt + 1, 1);
        PH_BAR();
        MFMA_QUAD(0, 1);
        PH_BAR();
        // ---- P3: A(qm1) reads; stage (tt+2).B0
#pragma unroll
        for (int ii = 0; ii < 4; ii++) {
            af[ii][0] = *(const short8*)&lds[lb + aL + (4+ii)*1024];
            af[ii][1] = *(const short8*)&lds[lb + aL + (4+ii)*1024 + 32];
        }
        stB(tt + 2, 0);
        PH_BAR();
        MFMA_QUAD(1, 0);
        PH_BAR();
        // ---- P4: stage (tt+2).B1; counted vmcnt gates tile tt+1
        stB(tt + 2, 1);
        CFENCE();
        __builtin_amdgcn_s_waitcnt(WAITCNT_VM4);
        __builtin_amdgcn_s_barrier();
        CFENCE();
        MFMA_QUAD(1, 1);
        PH_BAR();
    }
    __builtin_amdgcn_s_waitcnt(WAITCNT_VM0);  // drain dead stages before exit

    // epilogue: C/D layout col(n)=lane&15, row(m)=(lane>>4)*4+r
#pragma unroll
    for (int i = 0; i < 8; i++)
#pragma unroll
        for (int jj = 0; jj < 4; jj++) {
            int n = n0 + wnx*64 + jj*16 + ln;
            float bv = bias[n];
#pragma unroll
            for (int r = 0; r < 4; r++) {
                int m = m0 + wm*128 + i*16 + q*4 + r;   // = b*197 + t
                if (m < NROWS) {
                    float val = acc[i][jj][r] + bv;
                    if (LAYOUT == 1) {
                        int b = m / 197; int t = m - b*197;
                        int head = n >> 6; int d = n & 63;
                        size_t off = ((size_t)(t*NH + head)*BATCH + b)*64 + d;
                        ((uint16_t*)C)[off] = f2bf(val);
                    } else {
                        size_t off = (size_t)m * Ntot + n;
                        if (STORE_BF16) ((uint16_t*)C)[off] = f2bf(val);
                        else            ((float*)C)[off]    = val;
                    }
                }
            }
        }
}

// ---------------- fused bidirectional multi-head LSTM ----------------
// R2-proven structure + R6 cvt_pk pack (passed R6). grid (8,12,2), 256 thr.
__global__ __launch_bounds__(256) void lstm_fused(
    const uint16_t* __restrict__ pre,   // [T][head][B][64] bf16
    const uint16_t* __restrict__ wih_f, const uint16_t* __restrict__ whh_f,
    const uint16_t* __restrict__ wih_r, const uint16_t* __restrict__ whh_r,
    const float* __restrict__ bih_f, const float* __restrict__ bhh_f,
    const float* __restrict__ bih_r, const float* __restrict__ bhh_r,
    uint16_t* __restrict__ hout)        // [B][T][1536] bf16
{
    __shared__ __attribute__((aligned(16))) uint16_t hbuf[2][16][72];

    const int tid  = threadIdx.x;
    const int wv   = tid >> 6;
    const int lane = tid & 63;
    const int ln   = lane & 15;
    const int q    = lane >> 4;
    const int b0   = blockIdx.x * 16;
    const int head = blockIdx.y;
    const int dir  = blockIdx.z;
    const int ub   = wv * 16;

    const uint16_t* wih = dir ? wih_r : wih_f;
    const uint16_t* whh = dir ? whh_r : whh_f;
    const float*    bih = dir ? bih_r : bih_f;
    const float*    bhh = dir ? bhh_r : bhh_f;

    // persistent A-fragments: [gate type][k-step]
    short8 aih[4][2], ahh[4][2];
#pragma unroll
    for (int t = 0; t < 4; t++) {
        size_t row = (size_t)(t*768 + head*64 + ub + ln);
#pragma unroll
        for (int s = 0; s < 2; s++) {
            aih[t][s] = *(const short8*)(wih + row*768 + head*64 + s*32 + q*8);
            ahh[t][s] = *(const short8*)(whh + row*768 + head*64 + s*32 + q*8);
        }
    }
    float biasv[4][4];
#pragma unroll
    for (int t = 0; t < 4; t++)
#pragma unroll
        for (int r = 0; r < 4; r++) {
            int row = t*768 + head*64 + ub + q*4 + r;
            biasv[t][r] = bih[row] + bhh[row];
        }

    for (int i = tid; i < 2*16*72; i += 256) ((uint16_t*)hbuf)[i] = 0;
    float c[4] = {0.f, 0.f, 0.f, 0.f};
    __syncthreads();

    // x: [t][head][b][64]; wave reads 2 KB contiguous per step
    const uint16_t* xbase = pre + (size_t)head*BATCH*64 + (size_t)(b0 + ln)*64 + q*8;
    // direct h-store base: lane (ln,q) of wave wv owns units ub+q*4..+3, batch b0+ln
    uint16_t* hw = hout + ((size_t)(b0 + ln)*TT)*1536 + dir*768 + head*64 + ub + q*4;

    int t_cur = dir ? (TT - 1) : 0;
    const int tstep = dir ? -1 : 1;
    size_t xo = (size_t)t_cur * NH * BATCH * 64;
    short8 xv0 = *(const short8*)(xbase + xo);
    short8 xv1 = *(const short8*)(xbase + xo + 32);

    for (int step = 0; step < TT; step++) {
        short8 cx0 = xv0, cx1 = xv1;
        int t_next = t_cur + tstep;
        if (step + 1 < TT) {   // prefetch next timestep's x (coalesced)
            size_t xo2 = (size_t)t_next * NH * BATCH * 64;
            xv0 = *(const short8*)(xbase + xo2);
            xv1 = *(const short8*)(xbase + xo2 + 32);
        }
        const int pb = (step + 1) & 1;   // buffer holding h_{step-1}
        const int cb = step & 1;         // buffer to write h_step
        short8 hb0 = *(const short8*)&hbuf[pb][ln][0*32 + q*8];
        short8 hb1 = *(const short8*)&hbuf[pb][ln][1*32 + q*8];

        floatx4 acc[4];
#pragma unroll
        for (int t = 0; t < 4; t++)
            acc[t] = (floatx4){biasv[t][0], biasv[t][1], biasv[t][2], biasv[t][3]};
#pragma unroll
        for (int t = 0; t < 4; t++) {
            acc[t] = mfma16(aih[t][0], cx0, acc[t]);   // x part first: independent of hb
            acc[t] = mfma16(ahh[t][0], hb0, acc[t]);
            acc[t] = mfma16(aih[t][1], cx1, acc[t]);
            acc[t] = mfma16(ahh[t][1], hb1, acc[t]);
        }

        float hv[4];
#pragma unroll
        for (int r = 0; r < 4; r++) {
            float ig = sigf(acc[0][r]);
            float fg = sigf(acc[1][r]);
            float gg = tanhf_(acc[2][r]);
            float og = sigf(acc[3][r]);
            c[r] = fg * c[r] + ig * gg;
            hv[r] = og * tanhf_(c[r]);
        }
        // pack 4 fp32 -> 4 bf16 (RNE) in 2 instructions
        uint2 hp;
        asm volatile("v_cvt_pk_bf16_f32 %0, %1, %2" : "=v"(hp.x) : "v"(hv[0]), "v"(hv[1]));
        asm volatile("v_cvt_pk_bf16_f32 %0, %1, %2" : "=v"(hp.y) : "v"(hv[2]), "v"(hv[3]));

        // exchange write into the OTHER buffer (no conflict with laggard readers)
        *(uint2*)&hbuf[cb][ln][ub + q*4] = hp;
        // direct global store from C-layout regs: fire-and-forget, NOT drained below
        *(uint2*)(hw + (size_t)t_cur * 1536) = hp;

        CFENCE();
        __builtin_amdgcn_s_waitcnt(WAITCNT_LGKM0_ONLY);  // LDS write visible...
        __builtin_amdgcn_s_barrier();                     // ...to all waves
        CFENCE();

        t_cur = t_next;
    }
}

extern "C" void kernel_launch(void* const* d_in, const int* in_sizes, int n_in,
                              void* d_out, int out_size, void* d_ws, size_t ws_size,
                              hipStream_t stream) {
    (void)in_sizes; (void)n_in; (void)out_size; (void)ws_size;
    const float* x     = (const float*)d_in[0];
    const float* pre_w = (const float*)d_in[1];
    const float* pre_b = (const float*)d_in[2];
    const float* wihf  = (const float*)d_in[3];
    const float* whhf  = (const float*)d_in[4];
    const float* bihf  = (const float*)d_in[5];
    const float* bhhf  = (const float*)d_in[6];
    const float* wihr  = (const float*)d_in[7];
    const float* whhr  = (const float*)d_in[8];
    const float* bihr  = (const float*)d_in[9];
    const float* bhhr  = (const float*)d_in[10];
    const float* projw = (const float*)d_in[11];
    const float* projb = (const float*)d_in[12];
    float* out = (float*)d_out;

    // workspace layout (bf16 elements), ~177 MB total
    uint16_t* W = (uint16_t*)d_ws;
    uint16_t* xb     = W; W += (size_t)NROWS * DD;     // x bf16       [B*T][768]
    uint16_t* bwpre  = W; W += (size_t)DD * DD;
    uint16_t* bwihf  = W; W += (size_t)G4H * DD;
    uint16_t* bwhhf  = W; W += (size_t)G4H * DD;
    uint16_t* bwihr  = W; W += (size_t)G4H * DD;
    uint16_t* bwhhr  = W; W += (size_t)G4H * DD;
    uint16_t* bwproj = W; W += (size_t)DD * 2 * DD;
    uint16_t* preb   = W; W += (size_t)NROWS * DD;     // [T][head][B][64] bf16
    uint16_t* houtb  = W; W += (size_t)NROWS * 2 * DD; // [B][T][1536] bf16

    CvtArgs ca;
    ca.src[0] = x;     ca.dst[0] = xb;     ca.n4[0] = (int)((size_t)NROWS * DD / 4);
    ca.src[1] = pre_w; ca.dst[1] = bwpre;  ca.n4[1] = DD * DD / 4;
    ca.src[2] = wihf;  ca.dst[2] = bwihf;  ca.n4[2] = G4H * DD / 4;
    ca.src[3] = whhf;  ca.dst[3] = bwhhf;  ca.n4[3] = G4H * DD / 4;
    ca.src[4] = wihr;  ca.dst[4] = bwihr;  ca.n4[4] = G4H * DD / 4;
    ca.src[5] = whhr;  ca.dst[5] = bwhhr;  ca.n4[5] = G4H * DD / 4;
    ca.src[6] = projw; ca.dst[6] = bwproj; ca.n4[6] = DD * 2 * DD / 4;
    ca.nseg = 7;
    hipLaunchKernelGGL(cvt_multi, dim3(1024), dim3(256), 0, stream, ca);

    const int GBLK8 = MT8 * NT8;   // 297 blocks, bijective XCD swizzle in-kernel

    // S1: pre = x @ pre_w.T + pre_b, bf16, stored [t][head][b][64]
    hipLaunchKernelGGL((gemm256q<1, 1>), dim3(GBLK8), dim3(512), 0, stream,
                       xb, bwpre, pre_b, (void*)preb, DD, DD);
    // S2+S3: bidirectional block-diagonal LSTM
    hipLaunchKernelGGL(lstm_fused, dim3(8, 12, 2), dim3(256), 0, stream,
                       preb, bwihf, bwhhf, bwihr, bwhhr,
                       bihf, bhhf, bihr, bhhr, houtb);
    // S4: out = [hf|hr] @ proj_w.T + proj_b, fp32
    hipLaunchKernelGGL((gemm256q<0, 0>), dim3(GBLK8), dim3(512), 0, stream,
                       houtb, bwproj, projb, (void*)out, 2 * DD, DD);
}

// Round 8
// 477.814 us; speedup vs baseline: 1.0980x; 1.0980x over previous
//
#include <hip/hip_runtime.h>
#include <stdint.h>

// R8 = R7 + T2 st-style XOR swizzle on the 8-phase 256x256 GEMM's LDS
// (R7 counter evidence: SQ_LDS_BANK_CONFLICT 1.64e7/dispatch = 16-way ds_read
// conflict on 128-byte LDS rows; T2 is the measured +29-35% lever on exactly
// this 8-phase structure, m201).

#define DEV __device__ __forceinline__

typedef __attribute__((ext_vector_type(8))) short short8;
typedef __attribute__((ext_vector_type(4))) float floatx4;

// problem dims
#define BATCH 128
#define TT    197
#define DD    768
#define NH    12
#define NROWS (BATCH*TT)   // 25216 = 197*128
#define G4H   3072         // 4*H rows of gate weights
#define MT8   99           // m-tiles of 256 (last half-valid)
#define NT8   3            // n-tiles of 256

DEV uint16_t f2bf(float f) {
    union { float f; uint32_t u; } v; v.f = f;
    uint32_t r = (v.u + 0x7FFF + ((v.u >> 16) & 1)) >> 16;  // RNE
    return (uint16_t)r;
}

DEV floatx4 mfma16(short8 a, short8 b, floatx4 c) {
    return __builtin_amdgcn_mfma_f32_16x16x32_bf16(a, b, c, 0, 0, 0);
}

DEV float sigf(float x)   { return __builtin_amdgcn_rcpf(1.0f + __expf(-x)); }
DEV float tanhf_(float x) { return 1.0f - 2.0f * __builtin_amdgcn_rcpf(1.0f + __expf(2.0f * x)); }

// async global->LDS, 16B per lane; lds base must be wave-uniform (HW adds lane*16)
DEV void async16(const uint16_t* g, uint16_t* l) {
    __builtin_amdgcn_global_load_lds(
        (const __attribute__((address_space(1))) unsigned int*)g,
        (__attribute__((address_space(3))) unsigned int*)l,
        16, 0, 0);
}

#define CFENCE() asm volatile("" ::: "memory")
// s_waitcnt simm16 encoding (gfx9): vmcnt[3:0]|expcnt[6:4]|lgkmcnt[11:8]|vmcnt[5:4]@[15:14]
#define WAITCNT_LGKM0_ONLY 0xC07F   // lgkmcnt(0), vmcnt/expcnt = no-wait
#define WAITCNT_VM4        0x0F74   // vmcnt(4),   lgkm/expcnt  = no-wait
#define WAITCNT_VM0        0x0F70   // vmcnt(0),   lgkm/expcnt  = no-wait

// ---------------- fused fp32 -> bf16 conversion (all tensors, one launch) ----
struct CvtArgs {
    const float* src[7];
    uint16_t*    dst[7];
    int          n4[7];    // element count / 4
    int          nseg;
};

__global__ void cvt_multi(CvtArgs a) {
    int tid = blockIdx.x * blockDim.x + threadIdx.x;
    int stride = gridDim.x * blockDim.x;
    for (int s = 0; s < a.nseg; s++) {
        const float4* src = (const float4*)a.src[s];
        ushort4* dst = (ushort4*)a.dst[s];
        int n4 = a.n4[s];
        for (int i = tid; i < n4; i += stride) {
            float4 v = src[i];
            ushort4 o;
            o.x = f2bf(v.x); o.y = f2bf(v.y); o.z = f2bf(v.z); o.w = f2bf(v.w);
            dst[i] = o;
        }
    }
}

// ---------------- 8-phase 256x256 bf16 MFMA GEMM: C = A[M,K] @ Bw[N,K]^T + b --
// Structure as R7 (m201 template; phases/stage/vmcnt schedule unchanged,
// verified correct). NEW in R8: XOR-swizzled LDS (T2, rule #21 both-sides):
//   logical col k of tile row r lives at LDS slot k ^ ((r&7)*8)   [elements]
//   WRITE side: global_load_lds is linear, so each lane's GLOBAL k-offset is
//     pre-swizzled: kq8 = 8*((lane&7) ^ (lane>>3)); lane>>3 == tile-row&7
//     (chunks are 8-row aligned; boundary clamp changes only the global ROW,
//      swizzle keys on the destination tile row -> involution preserved).
//   READ side: col = (q*8 + s*32) ^ ((ln&7)*8).
// Bank math: slot v=q^(ln&7) -> 8 lanes per 4-bank group = exactly the b128
// minimum 8 touches/bank -> uniform = conflict-free (was: 16 lanes on 4 of 8
// groups = 2x serialization, 1.64e7 conflict cycles/dispatch).
// Phases per K-tile tt (buf = tt&1):
//   P1: read A(qm0)+B(qn0); stage (tt+1).A0 | P2: read B(qn1); stage (tt+1).A1
//   P3: read A(qm1); stage (tt+2).B0        | P4: stage (tt+2).B1 + VMCNT(4)
// vmcnt(4)@P4 retires through (tt+1).A1 -> tile tt+1 landed before its P1.
// Dead tail stages clamp k0=0 keeping counts exact. setprio around MFMA (T5).
// Bijective XCD swizzle (m204) for nwg=297. Boundary tile 98: rows clamped,
// stores guarded m<NROWS.
#define PH_BAR() do { CFENCE(); __builtin_amdgcn_s_barrier(); CFENCE(); } while(0)

#define MFMA_QUAD(QM, QN) do { \
    __builtin_amdgcn_s_setprio(1); \
    _Pragma("unroll") \
    for (int ii = 0; ii < 4; ii++) \
        _Pragma("unroll") \
        for (int j = 0; j < 2; j++) { \
            acc[(QM)*4+ii][(QN)*2+j] = mfma16(af[ii][0], bfr[QN][j][0], acc[(QM)*4+ii][(QN)*2+j]); \
            acc[(QM)*4+ii][(QN)*2+j] = mfma16(af[ii][1], bfr[QN][j][1], acc[(QM)*4+ii][(QN)*2+j]); \
        } \
    __builtin_amdgcn_s_setprio(0); \
} while(0)

template<int STORE_BF16, int LAYOUT>
__global__ __launch_bounds__(512, 2) void gemm256q(
    const uint16_t* __restrict__ A,    // [M][K] bf16
    const uint16_t* __restrict__ Bw,   // [N][K] bf16 (weight; transposed use)
    const float*    __restrict__ bias, // [N] fp32
    void*           __restrict__ C,
    int K, int Ntot)
{
    __shared__ __attribute__((aligned(16))) uint16_t lds[65536]; // A:[0,32K) B:[32K,64K) elems

    // bijective XCD swizzle (m204): nwg = 297 (not /8-divisible)
    const int nwg = gridDim.x;
    const int qq = nwg >> 3, rr = nwg & 7;
    const int xcd = blockIdx.x & 7, loc = blockIdx.x >> 3;
    const int swz = (xcd < rr ? xcd*(qq+1) : rr*(qq+1) + (xcd-rr)*qq) + loc;
    const int mt_ = swz / NT8, nt_ = swz - mt_*NT8;
    const int m0 = mt_*256, n0 = nt_*256;

    const int tid  = threadIdx.x;
    const int wv   = tid >> 6;        // 0..7
    const int lane = tid & 63;
    const int ln   = lane & 15;
    const int q    = lane >> 4;
    const int wm   = wv >> 2;         // 0..1: wave M-half
    const int wnx  = wv & 3;          // 0..3: wave N-quarter
    const int NKT  = K >> 6;          // K-tiles (12 or 24)

    floatx4 acc[8][4];
#pragma unroll
    for (int i = 0; i < 8; i++)
#pragma unroll
        for (int j = 0; j < 4; j++) acc[i][j] = (floatx4){0.f, 0.f, 0.f, 0.f};

    // staging source offsets: chunk c = wv*2+l covers rows [c*8, c*8+8) of a
    // 128-row half; lane: row c*8+(lane>>3). k-offset PRE-SWIZZLED (T2 write
    // side): lane's LDS slot colE=(lane&7)*8 must hold logical col
    // colE ^ ((row&7)*8), row&7 == lane>>3.
    const int c0   = wv * 2;
    const int rsub = lane >> 3;
    const int kq8  = 8 * ((lane & 7) ^ rsub);   // swizzled source k within tile
    uint32_t gA[2][2], gB[2][2];      // [half][l] element offsets
#pragma unroll
    for (int h = 0; h < 2; h++)
#pragma unroll
        for (int l = 0; l < 2; l++) {
            int row = m0 + h*128 + (c0 + l)*8 + rsub;
            if (row >= NROWS) row = NROWS - 1;   // boundary tile half1 clamp
            gA[h][l] = (uint32_t)row * (uint32_t)K + kq8;
            gB[h][l] = (uint32_t)(n0 + h*128 + (c0 + l)*8 + rsub) * (uint32_t)K + kq8;
        }

    // fragment read bases (LDS row-major [256][64] per buf) + T2 read swizzle
    const int swzE  = (ln & 7) * 8;            // element XOR mask, bits 3-5
    const int colR0 = (q*8)      ^ swzE;
    const int colR1 = (q*8 + 32) ^ swzE;
    const int aL = (wm*128 + ln)*64;           // + buf*16384 + ii*1024 + colR
    const int bL = 32768 + (wnx*64 + ln)*64;   // + buf*16384 + jj*1024 + colR

    auto stA = [&](int kt, int h) {
        uint32_t k0 = (kt < NKT) ? (uint32_t)(kt << 6) : 0u;  // dead stage clamp
        uint16_t* d = &lds[(kt & 1)*16384 + h*8192 + c0*512];
        async16(A + gA[h][0] + k0, d);
        async16(A + gA[h][1] + k0, d + 512);
    };
    auto stB = [&](int kt, int h) {
        uint32_t k0 = (kt < NKT) ? (uint32_t)(kt << 6) : 0u;
        uint16_t* d = &lds[32768 + (kt & 1)*16384 + h*8192 + c0*512];
        async16(Bw + gB[h][0] + k0, d);
        async16(Bw + gB[h][1] + k0, d + 512);
    };

    // prologue: tile0 full + tile1 B-halves (12 loads/wave); t0 landed gate
    stB(0,0); stB(0,1); stA(0,0); stA(0,1); stB(1,0); stB(1,1);
    CFENCE();
    __builtin_amdgcn_s_waitcnt(WAITCNT_VM4);
    __builtin_amdgcn_s_barrier();
    CFENCE();

    short8 af[4][2];        // A-frags of current qm
    short8 bfr[2][2][2];    // [qn][j][s], both qn sets live across P1..P4

    for (int tt = 0; tt < NKT; tt++) {
        const int lb = (tt & 1) * 16384;
        // ---- P1: A(qm0) + B(qn0) reads; stage (tt+1).A0
#pragma unroll
        for (int ii = 0; ii < 4; ii++) {
            af[ii][0] = *(const short8*)&lds[lb + aL + ii*1024 + colR0];
            af[ii][1] = *(const short8*)&lds[lb + aL + ii*1024 + colR1];
        }
#pragma unroll
        for (int j = 0; j < 2; j++) {
            bfr[0][j][0] = *(const short8*)&lds[lb + bL + j*1024 + colR0];
            bfr[0][j][1] = *(const short8*)&lds[lb + bL + j*1024 + colR1];
        }
        stA(tt + 1, 0);
        PH_BAR();
        MFMA_QUAD(0, 0);
        PH_BAR();
        // ---- P2: B(qn1) reads; stage (tt+1).A1
#pragma unroll
        for (int j = 0; j < 2; j++) {
            bfr[1][j][0] = *(const short8*)&lds[lb + bL + (2+j)*1024 + colR0];
            bfr[1][j][1] = *(const short8*)&lds[lb + bL + (2+j)*1024 + colR1];
        }
        stA(tt + 1, 1);
        PH_BAR();
        MFMA_QUAD(0, 1);
        PH_BAR();
        // ---- P3: A(qm1) reads; stage (tt+2).B0
#pragma unroll
        for (int ii = 0; ii < 4; ii++) {
            af[ii][0] = *(const short8*)&lds[lb + aL + (4+ii)*1024 + colR0];
            af[ii][1] = *(const short8*)&lds[lb + aL + (4+ii)*1024 + colR1];
        }
        stB(tt + 2, 0);
        PH_BAR();
        MFMA_QUAD(1, 0);
        PH_BAR();
        // ---- P4: stage (tt+2).B1; counted vmcnt gates tile tt+1
        stB(tt + 2, 1);
        CFENCE();
        __builtin_amdgcn_s_waitcnt(WAITCNT_VM4);
        __builtin_amdgcn_s_barrier();
        CFENCE();
        MFMA_QUAD(1, 1);
        PH_BAR();
    }
    __builtin_amdgcn_s_waitcnt(WAITCNT_VM0);  // drain dead stages before exit

    // epilogue: C/D layout col(n)=lane&15, row(m)=(lane>>4)*4+r
#pragma unroll
    for (int i = 0; i < 8; i++)
#pragma unroll
        for (int jj = 0; jj < 4; jj++) {
            int n = n0 + wnx*64 + jj*16 + ln;
            float bv = bias[n];
#pragma unroll
            for (int r = 0; r < 4; r++) {
                int m = m0 + wm*128 + i*16 + q*4 + r;   // = b*197 + t
                if (m < NROWS) {
                    float val = acc[i][jj][r] + bv;
                    if (LAYOUT == 1) {
                        int b = m / 197; int t = m - b*197;
                        int head = n >> 6; int d = n & 63;
                        size_t off = ((size_t)(t*NH + head)*BATCH + b)*64 + d;
                        ((uint16_t*)C)[off] = f2bf(val);
                    } else {
                        size_t off = (size_t)m * Ntot + n;
                        if (STORE_BF16) ((uint16_t*)C)[off] = f2bf(val);
                        else            ((float*)C)[off]    = val;
                    }
                }
            }
        }
}

// ---------------- fused bidirectional multi-head LSTM ----------------
// R2-proven structure + R6 cvt_pk pack (passed R6/R7). grid (8,12,2), 256 thr.
__global__ __launch_bounds__(256) void lstm_fused(
    const uint16_t* __restrict__ pre,   // [T][head][B][64] bf16
    const uint16_t* __restrict__ wih_f, const uint16_t* __restrict__ whh_f,
    const uint16_t* __restrict__ wih_r, const uint16_t* __restrict__ whh_r,
    const float* __restrict__ bih_f, const float* __restrict__ bhh_f,
    const float* __restrict__ bih_r, const float* __restrict__ bhh_r,
    uint16_t* __restrict__ hout)        // [B][T][1536] bf16
{
    __shared__ __attribute__((aligned(16))) uint16_t hbuf[2][16][72];

    const int tid  = threadIdx.x;
    const int wv   = tid >> 6;
    const int lane = tid & 63;
    const int ln   = lane & 15;
    const int q    = lane >> 4;
    const int b0   = blockIdx.x * 16;
    const int head = blockIdx.y;
    const int dir  = blockIdx.z;
    const int ub   = wv * 16;

    const uint16_t* wih = dir ? wih_r : wih_f;
    const uint16_t* whh = dir ? whh_r : whh_f;
    const float*    bih = dir ? bih_r : bih_f;
    const float*    bhh = dir ? bhh_r : bhh_f;

    // persistent A-fragments: [gate type][k-step]
    short8 aih[4][2], ahh[4][2];
#pragma unroll
    for (int t = 0; t < 4; t++) {
        size_t row = (size_t)(t*768 + head*64 + ub + ln);
#pragma unroll
        for (int s = 0; s < 2; s++) {
            aih[t][s] = *(const short8*)(wih + row*768 + head*64 + s*32 + q*8);
            ahh[t][s] = *(const short8*)(whh + row*768 + head*64 + s*32 + q*8);
        }
    }
    float biasv[4][4];
#pragma unroll
    for (int t = 0; t < 4; t++)
#pragma unroll
        for (int r = 0; r < 4; r++) {
            int row = t*768 + head*64 + ub + q*4 + r;
            biasv[t][r] = bih[row] + bhh[row];
        }

    for (int i = tid; i < 2*16*72; i += 256) ((uint16_t*)hbuf)[i] = 0;
    float c[4] = {0.f, 0.f, 0.f, 0.f};
    __syncthreads();

    // x: [t][head][b][64]; wave reads 2 KB contiguous per step
    const uint16_t* xbase = pre + (size_t)head*BATCH*64 + (size_t)(b0 + ln)*64 + q*8;
    // direct h-store base: lane (ln,q) of wave wv owns units ub+q*4..+3, batch b0+ln
    uint16_t* hw = hout + ((size_t)(b0 + ln)*TT)*1536 + dir*768 + head*64 + ub + q*4;

    int t_cur = dir ? (TT - 1) : 0;
    const int tstep = dir ? -1 : 1;
    size_t xo = (size_t)t_cur * NH * BATCH * 64;
    short8 xv0 = *(const short8*)(xbase + xo);
    short8 xv1 = *(const short8*)(xbase + xo + 32);

    for (int step = 0; step < TT; step++) {
        short8 cx0 = xv0, cx1 = xv1;
        int t_next = t_cur + tstep;
        if (step + 1 < TT) {   // prefetch next timestep's x (coalesced)
            size_t xo2 = (size_t)t_next * NH * BATCH * 64;
            xv0 = *(const short8*)(xbase + xo2);
            xv1 = *(const short8*)(xbase + xo2 + 32);
        }
        const int pb = (step + 1) & 1;   // buffer holding h_{step-1}
        const int cb = step & 1;         // buffer to write h_step
        short8 hb0 = *(const short8*)&hbuf[pb][ln][0*32 + q*8];
        short8 hb1 = *(const short8*)&hbuf[pb][ln][1*32 + q*8];

        floatx4 acc[4];
#pragma unroll
        for (int t = 0; t < 4; t++)
            acc[t] = (floatx4){biasv[t][0], biasv[t][1], biasv[t][2], biasv[t][3]};
#pragma unroll
        for (int t = 0; t < 4; t++) {
            acc[t] = mfma16(aih[t][0], cx0, acc[t]);   // x part first: independent of hb
            acc[t] = mfma16(ahh[t][0], hb0, acc[t]);
            acc[t] = mfma16(aih[t][1], cx1, acc[t]);
            acc[t] = mfma16(ahh[t][1], hb1, acc[t]);
        }

        float hv[4];
#pragma unroll
        for (int r = 0; r < 4; r++) {
            float ig = sigf(acc[0][r]);
            float fg = sigf(acc[1][r]);
            float gg = tanhf_(acc[2][r]);
            float og = sigf(acc[3][r]);
            c[r] = fg * c[r] + ig * gg;
            hv[r] = og * tanhf_(c[r]);
        }
        // pack 4 fp32 -> 4 bf16 (RNE) in 2 instructions
        uint2 hp;
        asm volatile("v_cvt_pk_bf16_f32 %0, %1, %2" : "=v"(hp.x) : "v"(hv[0]), "v"(hv[1]));
        asm volatile("v_cvt_pk_bf16_f32 %0, %1, %2" : "=v"(hp.y) : "v"(hv[2]), "v"(hv[3]));

        // exchange write into the OTHER buffer (no conflict with laggard readers)
        *(uint2*)&hbuf[cb][ln][ub + q*4] = hp;
        // direct global store from C-layout regs: fire-and-forget, NOT drained below
        *(uint2*)(hw + (size_t)t_cur * 1536) = hp;

        CFENCE();
        __builtin_amdgcn_s_waitcnt(WAITCNT_LGKM0_ONLY);  // LDS write visible...
        __builtin_amdgcn_s_barrier();                     // ...to all waves
        CFENCE();

        t_cur = t_next;
    }
}

extern "C" void kernel_launch(void* const* d_in, const int* in_sizes, int n_in,
                              void* d_out, int out_size, void* d_ws, size_t ws_size,
                              hipStream_t stream) {
    (void)in_sizes; (void)n_in; (void)out_size; (void)ws_size;
    const float* x     = (const float*)d_in[0];
    const float* pre_w = (const float*)d_in[1];
    const float* pre_b = (const float*)d_in[2];
    const float* wihf  = (const float*)d_in[3];
    const float* whhf  = (const float*)d_in[4];
    const float* bihf  = (const float*)d_in[5];
    const float* bhhf  = (const float*)d_in[6];
    const float* wihr  = (const float*)d_in[7];
    const float* whhr  = (const float*)d_in[8];
    const float* bihr  = (const float*)d_in[9];
    const float* bhhr  = (const float*)d_in[10];
    const float* projw = (const float*)d_in[11];
    const float* projb = (const float*)d_in[12];
    float* out = (float*)d_out;

    // workspace layout (bf16 elements), ~177 MB total
    uint16_t* W = (uint16_t*)d_ws;
    uint16_t* xb     = W; W += (size_t)NROWS * DD;     // x bf16       [B*T][768]
    uint16_t* bwpre  = W; W += (size_t)DD * DD;
    uint16_t* bwihf  = W; W += (size_t)G4H * DD;
    uint16_t* bwhhf  = W; W += (size_t)G4H * DD;
    uint16_t* bwihr  = W; W += (size_t)G4H * DD;
    uint16_t* bwhhr  = W; W += (size_t)G4H * DD;
    uint16_t* bwproj = W; W += (size_t)DD * 2 * DD;
    uint16_t* preb   = W; W += (size_t)NROWS * DD;     // [T][head][B][64] bf16
    uint16_t* houtb  = W; W += (size_t)NROWS * 2 * DD; // [B][T][1536] bf16

    CvtArgs ca;
    ca.src[0] = x;     ca.dst[0] = xb;     ca.n4[0] = (int)((size_t)NROWS * DD / 4);
    ca.src[1] = pre_w; ca.dst[1] = bwpre;  ca.n4[1] = DD * DD / 4;
    ca.src[2] = wihf;  ca.dst[2] = bwihf;  ca.n4[2] = G4H * DD / 4;
    ca.src[3] = whhf;  ca.dst[3] = bwhhf;  ca.n4[3] = G4H * DD / 4;
    ca.src[4] = wihr;  ca.dst[4] = bwihr;  ca.n4[4] = G4H * DD / 4;
    ca.src[5] = whhr;  ca.dst[5] = bwhhr;  ca.n4[5] = G4H * DD / 4;
    ca.src[6] = projw; ca.dst[6] = bwproj; ca.n4[6] = DD * 2 * DD / 4;
    ca.nseg = 7;
    hipLaunchKernelGGL(cvt_multi, dim3(1024), dim3(256), 0, stream, ca);

    const int GBLK8 = MT8 * NT8;   // 297 blocks, bijective XCD swizzle in-kernel

    // S1: pre = x @ pre_w.T + pre_b, bf16, stored [t][head][b][64]
    hipLaunchKernelGGL((gemm256q<1, 1>), dim3(GBLK8), dim3(512), 0, stream,
                       xb, bwpre, pre_b, (void*)preb, DD, DD);
    // S2+S3: bidirectional block-diagonal LSTM
    hipLaunchKernelGGL(lstm_fused, dim3(8, 12, 2), dim3(256), 0, stream,
                       preb, bwihf, bwhhf, bwihr, bwhhr,
                       bihf, bhhf, bihr, bhhr, houtb);
    // S4: out = [hf|hr] @ proj_w.T + proj_b, fp32
    hipLaunchKernelGGL((gemm256q<0, 0>), dim3(GBLK8), dim3(512), 0, stream,
                       houtb, bwproj, projb, (void*)out, 2 * DD, DD);
}

// Round 9
// 462.211 us; speedup vs baseline: 1.1351x; 1.0338x over previous
//
#include <hip/hip_runtime.h>
#include <stdint.h>

// R9 = R8 (gemm256q unchanged) + LSTM serial-path surgery:
//   (1) xacc split: x-part MFMAs of step t+1 issue during step t's activation
//       window; post-barrier chain = 2 dependent hh-MFMAs (C-operand = xacc).
//   (2) log2e folded into gate weights (cvt) -> activations are pure
//       rcp(1+exp2(+/-z)), negation via operand modifier.
//   (3) depth-2 x prefetch, ping-pong reg pairs, loop unrolled x2 (rule #20).

#define DEV __device__ __forceinline__

typedef __attribute__((ext_vector_type(8))) short short8;
typedef __attribute__((ext_vector_type(4))) float floatx4;

// problem dims
#define BATCH 128
#define TT    197
#define DD    768
#define NH    12
#define NROWS (BATCH*TT)   // 25216 = 197*128
#define G4H   3072         // 4*H rows of gate weights
#define MT8   99           // m-tiles of 256 (last half-valid)
#define NT8   3            // n-tiles of 256

#define LOG2E  1.4426950408889634f
#define LOG2E2 2.8853900817779268f

DEV uint16_t f2bf(float f) {
    union { float f; uint32_t u; } v; v.f = f;
    uint32_t r = (v.u + 0x7FFF + ((v.u >> 16) & 1)) >> 16;  // RNE
    return (uint16_t)r;
}

DEV floatx4 mfma16(short8 a, short8 b, floatx4 c) {
    return __builtin_amdgcn_mfma_f32_16x16x32_bf16(a, b, c, 0, 0, 0);
}

DEV float exp2pos(float x) { float r; asm("v_exp_f32 %0, %1"  : "=v"(r) : "v"(x)); return r; }
DEV float exp2neg(float x) { float r; asm("v_exp_f32 %0, -%1" : "=v"(r) : "v"(x)); return r; }

// async global->LDS, 16B per lane; lds base must be wave-uniform (HW adds lane*16)
DEV void async16(const uint16_t* g, uint16_t* l) {
    __builtin_amdgcn_global_load_lds(
        (const __attribute__((address_space(1))) unsigned int*)g,
        (__attribute__((address_space(3))) unsigned int*)l,
        16, 0, 0);
}

#define CFENCE() asm volatile("" ::: "memory")
// s_waitcnt simm16 encoding (gfx9): vmcnt[3:0]|expcnt[6:4]|lgkmcnt[11:8]|vmcnt[5:4]@[15:14]
#define WAITCNT_LGKM0_ONLY 0xC07F   // lgkmcnt(0), vmcnt/expcnt = no-wait
#define WAITCNT_VM4        0x0F74   // vmcnt(4),   lgkm/expcnt  = no-wait
#define WAITCNT_VM0        0x0F70   // vmcnt(0),   lgkm/expcnt  = no-wait

// ---------------- fused fp32 -> bf16 conversion (all tensors, one launch) ----
// gscale=1 segments ([3072][768] gate weights): rows scaled by log2e
// (gate g rows x 2*log2e) so the LSTM activations can use raw v_exp_f32.
struct CvtArgs {
    const float* src[7];
    uint16_t*    dst[7];
    int          n4[7];    // element count / 4
    int          gscale[7];
    int          nseg;
};

__global__ void cvt_multi(CvtArgs a) {
    int tid = blockIdx.x * blockDim.x + threadIdx.x;
    int stride = gridDim.x * blockDim.x;
    for (int s = 0; s < a.nseg; s++) {
        const float4* src = (const float4*)a.src[s];
        ushort4* dst = (ushort4*)a.dst[s];
        int n4 = a.n4[s];
        int gs = a.gscale[s];
        for (int i = tid; i < n4; i += stride) {
            float4 v = src[i];
            if (gs) {
                int gate = i / 147456;           // i*4/768 = row; row/768 = gate
                float sc = (gate == 2) ? LOG2E2 : LOG2E;
                v.x *= sc; v.y *= sc; v.z *= sc; v.w *= sc;
            }
            ushort4 o;
            o.x = f2bf(v.x); o.y = f2bf(v.y); o.z = f2bf(v.z); o.w = f2bf(v.w);
            dst[i] = o;
        }
    }
}

// ---------------- 8-phase 256x256 bf16 MFMA GEMM: C = A[M,K] @ Bw[N,K]^T + b --
// R8-proven (T2 swizzle removed the 1.64e7 bank-conflict cycles; gemm now
// < lstm in dur). Byte-identical to R8.
#define PH_BAR() do { CFENCE(); __builtin_amdgcn_s_barrier(); CFENCE(); } while(0)

#define MFMA_QUAD(QM, QN) do { \
    __builtin_amdgcn_s_setprio(1); \
    _Pragma("unroll") \
    for (int ii = 0; ii < 4; ii++) \
        _Pragma("unroll") \
        for (int j = 0; j < 2; j++) { \
            acc[(QM)*4+ii][(QN)*2+j] = mfma16(af[ii][0], bfr[QN][j][0], acc[(QM)*4+ii][(QN)*2+j]); \
            acc[(QM)*4+ii][(QN)*2+j] = mfma16(af[ii][1], bfr[QN][j][1], acc[(QM)*4+ii][(QN)*2+j]); \
        } \
    __builtin_amdgcn_s_setprio(0); \
} while(0)

template<int STORE_BF16, int LAYOUT>
__global__ __launch_bounds__(512, 2) void gemm256q(
    const uint16_t* __restrict__ A,    // [M][K] bf16
    const uint16_t* __restrict__ Bw,   // [N][K] bf16 (weight; transposed use)
    const float*    __restrict__ bias, // [N] fp32
    void*           __restrict__ C,
    int K, int Ntot)
{
    __shared__ __attribute__((aligned(16))) uint16_t lds[65536]; // A:[0,32K) B:[32K,64K) elems

    // bijective XCD swizzle (m204): nwg = 297 (not /8-divisible)
    const int nwg = gridDim.x;
    const int qq = nwg >> 3, rr = nwg & 7;
    const int xcd = blockIdx.x & 7, loc = blockIdx.x >> 3;
    const int swz = (xcd < rr ? xcd*(qq+1) : rr*(qq+1) + (xcd-rr)*qq) + loc;
    const int mt_ = swz / NT8, nt_ = swz - mt_*NT8;
    const int m0 = mt_*256, n0 = nt_*256;

    const int tid  = threadIdx.x;
    const int wv   = tid >> 6;        // 0..7
    const int lane = tid & 63;
    const int ln   = lane & 15;
    const int q    = lane >> 4;
    const int wm   = wv >> 2;         // 0..1: wave M-half
    const int wnx  = wv & 3;          // 0..3: wave N-quarter
    const int NKT  = K >> 6;          // K-tiles (12 or 24)

    floatx4 acc[8][4];
#pragma unroll
    for (int i = 0; i < 8; i++)
#pragma unroll
        for (int j = 0; j < 4; j++) acc[i][j] = (floatx4){0.f, 0.f, 0.f, 0.f};

    // staging source offsets: chunk c = wv*2+l covers rows [c*8, c*8+8) of a
    // 128-row half; lane: row c*8+(lane>>3). k-offset PRE-SWIZZLED (T2 write
    // side): lane's LDS slot colE=(lane&7)*8 must hold logical col
    // colE ^ ((row&7)*8), row&7 == lane>>3.
    const int c0   = wv * 2;
    const int rsub = lane >> 3;
    const int kq8  = 8 * ((lane & 7) ^ rsub);   // swizzled source k within tile
    uint32_t gA[2][2], gB[2][2];      // [half][l] element offsets
#pragma unroll
    for (int h = 0; h < 2; h++)
#pragma unroll
        for (int l = 0; l < 2; l++) {
            int row = m0 + h*128 + (c0 + l)*8 + rsub;
            if (row >= NROWS) row = NROWS - 1;   // boundary tile half1 clamp
            gA[h][l] = (uint32_t)row * (uint32_t)K + kq8;
            gB[h][l] = (uint32_t)(n0 + h*128 + (c0 + l)*8 + rsub) * (uint32_t)K + kq8;
        }

    // fragment read bases (LDS row-major [256][64] per buf) + T2 read swizzle
    const int swzE  = (ln & 7) * 8;            // element XOR mask, bits 3-5
    const int colR0 = (q*8)      ^ swzE;
    const int colR1 = (q*8 + 32) ^ swzE;
    const int aL = (wm*128 + ln)*64;           // + buf*16384 + ii*1024 + colR
    const int bL = 32768 + (wnx*64 + ln)*64;   // + buf*16384 + jj*1024 + colR

    auto stA = [&](int kt, int h) {
        uint32_t k0 = (kt < NKT) ? (uint32_t)(kt << 6) : 0u;  // dead stage clamp
        uint16_t* d = &lds[(kt & 1)*16384 + h*8192 + c0*512];
        async16(A + gA[h][0] + k0, d);
        async16(A + gA[h][1] + k0, d + 512);
    };
    auto stB = [&](int kt, int h) {
        uint32_t k0 = (kt < NKT) ? (uint32_t)(kt << 6) : 0u;
        uint16_t* d = &lds[32768 + (kt & 1)*16384 + h*8192 + c0*512];
        async16(Bw + gB[h][0] + k0, d);
        async16(Bw + gB[h][1] + k0, d + 512);
    };

    // prologue: tile0 full + tile1 B-halves (12 loads/wave); t0 landed gate
    stB(0,0); stB(0,1); stA(0,0); stA(0,1); stB(1,0); stB(1,1);
    CFENCE();
    __builtin_amdgcn_s_waitcnt(WAITCNT_VM4);
    __builtin_amdgcn_s_barrier();
    CFENCE();

    short8 af[4][2];        // A-frags of current qm
    short8 bfr[2][2][2];    // [qn][j][s], both qn sets live across P1..P4

    for (int tt = 0; tt < NKT; tt++) {
        const int lb = (tt & 1) * 16384;
        // ---- P1: A(qm0) + B(qn0) reads; stage (tt+1).A0
#pragma unroll
        for (int ii = 0; ii < 4; ii++) {
            af[ii][0] = *(const short8*)&lds[lb + aL + ii*1024 + colR0];
            af[ii][1] = *(const short8*)&lds[lb + aL + ii*1024 + colR1];
        }
#pragma unroll
        for (int j = 0; j < 2; j++) {
            bfr[0][j][0] = *(const short8*)&lds[lb + bL + j*1024 + colR0];
            bfr[0][j][1] = *(const short8*)&lds[lb + bL + j*1024 + colR1];
        }
        stA(tt + 1, 0);
        PH_BAR();
        MFMA_QUAD(0, 0);
        PH_BAR();
        // ---- P2: B(qn1) reads; stage (tt+1).A1
#pragma unroll
        for (int j = 0; j < 2; j++) {
            bfr[1][j][0] = *(const short8*)&lds[lb + bL + (2+j)*1024 + colR0];
            bfr[1][j][1] = *(const short8*)&lds[lb + bL + (2+j)*1024 + colR1];
        }
        stA(tt + 1, 1);
        PH_BAR();
        MFMA_QUAD(0, 1);
        PH_BAR();
        // ---- P3: A(qm1) reads; stage (tt+2).B0
#pragma unroll
        for (int ii = 0; ii < 4; ii++) {
            af[ii][0] = *(const short8*)&lds[lb + aL + (4+ii)*1024 + colR0];
            af[ii][1] = *(const short8*)&lds[lb + aL + (4+ii)*1024 + colR1];
        }
        stB(tt + 2, 0);
        PH_BAR();
        MFMA_QUAD(1, 0);
        PH_BAR();
        // ---- P4: stage (tt+2).B1; counted vmcnt gates tile tt+1
        stB(tt + 2, 1);
        CFENCE();
        __builtin_amdgcn_s_waitcnt(WAITCNT_VM4);
        __builtin_amdgcn_s_barrier();
        CFENCE();
        MFMA_QUAD(1, 1);
        PH_BAR();
    }
    __builtin_amdgcn_s_waitcnt(WAITCNT_VM0);  // drain dead stages before exit

    // epilogue: C/D layout col(n)=lane&15, row(m)=(lane>>4)*4+r
#pragma unroll
    for (int i = 0; i < 8; i++)
#pragma unroll
        for (int jj = 0; jj < 4; jj++) {
            int n = n0 + wnx*64 + jj*16 + ln;
            float bv = bias[n];
#pragma unroll
            for (int r = 0; r < 4; r++) {
                int m = m0 + wm*128 + i*16 + q*4 + r;   // = b*197 + t
                if (m < NROWS) {
                    float val = acc[i][jj][r] + bv;
                    if (LAYOUT == 1) {
                        int b = m / 197; int t = m - b*197;
                        int head = n >> 6; int d = n & 63;
                        size_t off = ((size_t)(t*NH + head)*BATCH + b)*64 + d;
                        ((uint16_t*)C)[off] = f2bf(val);
                    } else {
                        size_t off = (size_t)m * Ntot + n;
                        if (STORE_BF16) ((uint16_t*)C)[off] = f2bf(val);
                        else            ((float*)C)[off]    = val;
                    }
                }
            }
        }
}

// ---------------- fused bidirectional multi-head LSTM (R9 restructure) -------
// grid (8 batch-chunks, 12 heads, 2 dirs), 256 threads = 4 waves (1/SIMD).
// Wave w owns units [16w,16w+16). Post-barrier critical chain is now only:
// ds_read h -> 2 dependent hh-MFMAs (C-in = xacc, precomputed) -> activations.
// The x-part MFMAs for step s+1 issue during step s's activation window
// (independent of h). Gate weights pre-scaled by log2e (g-gate 2*log2e) in
// cvt -> sigmoid = rcp(1+exp2(-z)), tanh = 1-2*rcp(1+exp2(z)), negation free.
// Depth-2 x prefetch via ping-pong reg pairs; loop unrolled x2 so all reg
// indices are static (rule #20).
__global__ __launch_bounds__(256, 1) void lstm_fused(
    const uint16_t* __restrict__ pre,   // [T][head][B][64] bf16
    const uint16_t* __restrict__ wih_f, const uint16_t* __restrict__ whh_f,
    const uint16_t* __restrict__ wih_r, const uint16_t* __restrict__ whh_r,
    const float* __restrict__ bih_f, const float* __restrict__ bhh_f,
    const float* __restrict__ bih_r, const float* __restrict__ bhh_r,
    uint16_t* __restrict__ hout)        // [B][T][1536] bf16
{
    __shared__ __attribute__((aligned(16))) uint16_t hbuf[2][16][72];

    const int tid  = threadIdx.x;
    const int wv   = tid >> 6;
    const int lane = tid & 63;
    const int ln   = lane & 15;
    const int q    = lane >> 4;
    const int b0   = blockIdx.x * 16;
    const int head = blockIdx.y;
    const int dir  = blockIdx.z;
    const int ub   = wv * 16;

    const uint16_t* wih = dir ? wih_r : wih_f;
    const uint16_t* whh = dir ? whh_r : whh_f;
    const float*    bih = dir ? bih_r : bih_f;
    const float*    bhh = dir ? bhh_r : bhh_f;

    // persistent A-fragments: [gate type][k-step] (weights pre-scaled in cvt)
    short8 aih[4][2], ahh[4][2];
#pragma unroll
    for (int t = 0; t < 4; t++) {
        size_t row = (size_t)(t*768 + head*64 + ub + ln);
#pragma unroll
        for (int s = 0; s < 2; s++) {
            aih[t][s] = *(const short8*)(wih + row*768 + head*64 + s*32 + q*8);
            ahh[t][s] = *(const short8*)(whh + row*768 + head*64 + s*32 + q*8);
        }
    }
    floatx4 bias4[4];
#pragma unroll
    for (int t = 0; t < 4; t++) {
        const float gsc = (t == 2) ? LOG2E2 : LOG2E;
#pragma unroll
        for (int r = 0; r < 4; r++) {
            int row = t*768 + head*64 + ub + q*4 + r;
            bias4[t][r] = (bih[row] + bhh[row]) * gsc;
        }
    }

    for (int i = tid; i < 2*16*72; i += 256) ((uint16_t*)hbuf)[i] = 0;
    float c[4] = {0.f, 0.f, 0.f, 0.f};
    __syncthreads();

    const ptrdiff_t XS = (ptrdiff_t)NH * BATCH * 64;   // 98304 elems per t
    const int ts = dir ? -1 : 1;
    const int t0 = dir ? (TT - 1) : 0;
    const uint16_t* xbase = pre + (size_t)head*BATCH*64 + (size_t)(b0 + ln)*64 + q*8;
    uint16_t* hst = hout + ((size_t)(b0 + ln)*TT)*1536 + dir*768 + head*64 + ub + q*4
                    + (ptrdiff_t)t0 * 1536;
    const ptrdiff_t HSTEP = (ptrdiff_t)ts * 1536;

    // xacc for step 0 (bias + W_ih x; hh part joins post-barrier each step)
    floatx4 xacc[4];
    {
        const uint16_t* xp = xbase + (ptrdiff_t)t0 * XS;
        short8 x0 = *(const short8*)xp;
        short8 x1 = *(const short8*)(xp + 32);
#pragma unroll
        for (int t = 0; t < 4; t++) {
            xacc[t] = bias4[t];
            xacc[t] = mfma16(aih[t][0], x0, xacc[t]);
            xacc[t] = mfma16(aih[t][1], x1, xacc[t]);
        }
    }
    // depth-2 prefetch: A pair = x_{step1}, B pair = x_{step2}
    short8 xa0, xa1, xb0, xb1;
    {
        const uint16_t* p1 = xbase + (ptrdiff_t)(t0 + ts) * XS;
        const uint16_t* p2 = xbase + (ptrdiff_t)(t0 + 2*ts) * XS;
        xa0 = *(const short8*)p1; xa1 = *(const short8*)(p1 + 32);
        xb0 = *(const short8*)p2; xb1 = *(const short8*)(p2 + 32);
    }
    const uint16_t* xload = xbase + (ptrdiff_t)(t0 + 3*ts) * XS;
    const ptrdiff_t XSTEP = (ptrdiff_t)ts * XS;

    auto body = [&](int s, short8& nx0, short8& nx1, int PB, int CB) {
        short8 hb0 = *(const short8*)&hbuf[PB][ln][q*8];
        short8 hb1 = *(const short8*)&hbuf[PB][ln][32 + q*8];
        floatx4 g[4];
#pragma unroll
        for (int t = 0; t < 4; t++) {
            g[t] = mfma16(ahh[t][0], hb0, xacc[t]);   // C-in = precomputed xacc
            g[t] = mfma16(ahh[t][1], hb1, g[t]);      // only 2 dep MFMAs on path
        }
        // renew xacc for step s+1 (overlaps activation/hh latency below)
#pragma unroll
        for (int t = 0; t < 4; t++) {
            xacc[t] = bias4[t];
            xacc[t] = mfma16(aih[t][0], nx0, xacc[t]);
            xacc[t] = mfma16(aih[t][1], nx1, xacc[t]);
        }
        if (s + 3 < TT) {   // refill just-consumed pair with x_{s+3} (depth 2)
            nx0 = *(const short8*)xload;
            nx1 = *(const short8*)(xload + 32);
        }
        xload += XSTEP;

        float hv[4];
#pragma unroll
        for (int r = 0; r < 4; r++) {
            float ig = __builtin_amdgcn_rcpf(1.f + exp2neg(g[0][r]));
            float fg = __builtin_amdgcn_rcpf(1.f + exp2neg(g[1][r]));
            float gg = 1.f - 2.f*__builtin_amdgcn_rcpf(1.f + exp2pos(g[2][r]));
            float og = __builtin_amdgcn_rcpf(1.f + exp2neg(g[3][r]));
            c[r] = fg*c[r] + ig*gg;
            float th = 1.f - 2.f*__builtin_amdgcn_rcpf(1.f + exp2pos(c[r]*LOG2E2));
            hv[r] = og*th;
        }
        uint2 hp;
        asm volatile("v_cvt_pk_bf16_f32 %0, %1, %2" : "=v"(hp.x) : "v"(hv[0]), "v"(hv[1]));
        asm volatile("v_cvt_pk_bf16_f32 %0, %1, %2" : "=v"(hp.y) : "v"(hv[2]), "v"(hv[3]));

        *(uint2*)&hbuf[CB][ln][ub + q*4] = hp;   // exchange (other buffer)
        *(uint2*)hst = hp;                       // global store, fire-and-forget
        hst += HSTEP;

        CFENCE();
        __builtin_amdgcn_s_waitcnt(WAITCNT_LGKM0_ONLY);  // LDS write visible...
        __builtin_amdgcn_s_barrier();                     // ...to all waves
        CFENCE();
    };

    // steps 0..195 in pairs (static parity); step 196 peeled below
    for (int s = 0; s < TT - 1; s += 2) {
        body(s,     xa0, xa1, 1, 0);
        body(s + 1, xb0, xb1, 0, 1);
    }
    // final step s=196 (even): reads hbuf[1]; no renew/exchange/barrier needed
    {
        short8 hb0 = *(const short8*)&hbuf[1][ln][q*8];
        short8 hb1 = *(const short8*)&hbuf[1][ln][32 + q*8];
        floatx4 g[4];
#pragma unroll
        for (int t = 0; t < 4; t++) {
            g[t] = mfma16(ahh[t][0], hb0, xacc[t]);
            g[t] = mfma16(ahh[t][1], hb1, g[t]);
        }
        float hv[4];
#pragma unroll
        for (int r = 0; r < 4; r++) {
            float ig = __builtin_amdgcn_rcpf(1.f + exp2neg(g[0][r]));
            float fg = __builtin_amdgcn_rcpf(1.f + exp2neg(g[1][r]));
            float gg = 1.f - 2.f*__builtin_amdgcn_rcpf(1.f + exp2pos(g[2][r]));
            float og = __builtin_amdgcn_rcpf(1.f + exp2neg(g[3][r]));
            c[r] = fg*c[r] + ig*gg;
            float th = 1.f - 2.f*__builtin_amdgcn_rcpf(1.f + exp2pos(c[r]*LOG2E2));
            hv[r] = og*th;
        }
        uint2 hp;
        asm volatile("v_cvt_pk_bf16_f32 %0, %1, %2" : "=v"(hp.x) : "v"(hv[0]), "v"(hv[1]));
        asm volatile("v_cvt_pk_bf16_f32 %0, %1, %2" : "=v"(hp.y) : "v"(hv[2]), "v"(hv[3]));
        *(uint2*)hst = hp;
    }
}

extern "C" void kernel_launch(void* const* d_in, const int* in_sizes, int n_in,
                              void* d_out, int out_size, void* d_ws, size_t ws_size,
                              hipStream_t stream) {
    (void)in_sizes; (void)n_in; (void)out_size; (void)ws_size;
    const float* x     = (const float*)d_in[0];
    const float* pre_w = (const float*)d_in[1];
    const float* pre_b = (const float*)d_in[2];
    const float* wihf  = (const float*)d_in[3];
    const float* whhf  = (const float*)d_in[4];
    const float* bihf  = (const float*)d_in[5];
    const float* bhhf  = (const float*)d_in[6];
    const float* wihr  = (const float*)d_in[7];
    const float* whhr  = (const float*)d_in[8];
    const float* bihr  = (const float*)d_in[9];
    const float* bhhr  = (const float*)d_in[10];
    const float* projw = (const float*)d_in[11];
    const float* projb = (const float*)d_in[12];
    float* out = (float*)d_out;

    // workspace layout (bf16 elements), ~177 MB total
    uint16_t* W = (uint16_t*)d_ws;
    uint16_t* xb     = W; W += (size_t)NROWS * DD;     // x bf16       [B*T][768]
    uint16_t* bwpre  = W; W += (size_t)DD * DD;
    uint16_t* bwihf  = W; W += (size_t)G4H * DD;
    uint16_t* bwhhf  = W; W += (size_t)G4H * DD;
    uint16_t* bwihr  = W; W += (size_t)G4H * DD;
    uint16_t* bwhhr  = W; W += (size_t)G4H * DD;
    uint16_t* bwproj = W; W += (size_t)DD * 2 * DD;
    uint16_t* preb   = W; W += (size_t)NROWS * DD;     // [T][head][B][64] bf16
    uint16_t* houtb  = W; W += (size_t)NROWS * 2 * DD; // [B][T][1536] bf16

    CvtArgs ca;
    ca.src[0] = x;     ca.dst[0] = xb;     ca.n4[0] = (int)((size_t)NROWS * DD / 4); ca.gscale[0] = 0;
    ca.src[1] = pre_w; ca.dst[1] = bwpre;  ca.n4[1] = DD * DD / 4;                    ca.gscale[1] = 0;
    ca.src[2] = wihf;  ca.dst[2] = bwihf;  ca.n4[2] = G4H * DD / 4;                   ca.gscale[2] = 1;
    ca.src[3] = whhf;  ca.dst[3] = bwhhf;  ca.n4[3] = G4H * DD / 4;                   ca.gscale[3] = 1;
    ca.src[4] = wihr;  ca.dst[4] = bwihr;  ca.n4[4] = G4H * DD / 4;                   ca.gscale[4] = 1;
    ca.src[5] = whhr;  ca.dst[5] = bwhhr;  ca.n4[5] = G4H * DD / 4;                   ca.gscale[5] = 1;
    ca.src[6] = projw; ca.dst[6] = bwproj; ca.n4[6] = DD * 2 * DD / 4;                ca.gscale[6] = 0;
    ca.nseg = 7;
    hipLaunchKernelGGL(cvt_multi, dim3(1024), dim3(256), 0, stream, ca);

    const int GBLK8 = MT8 * NT8;   // 297 blocks, bijective XCD swizzle in-kernel

    // S1: pre = x @ pre_w.T + pre_b, bf16, stored [t][head][b][64]
    hipLaunchKernelGGL((gemm256q<1, 1>), dim3(GBLK8), dim3(512), 0, stream,
                       xb, bwpre, pre_b, (void*)preb, DD, DD);
    // S2+S3: bidirectional block-diagonal LSTM
    hipLaunchKernelGGL(lstm_fused, dim3(8, 12, 2), dim3(256), 0, stream,
                       preb, bwihf, bwhhf, bwihr, bwhhr,
                       bihf, bhhf, bihr, bhhr, houtb);
    // S4: out = [hf|hr] @ proj_w.T + proj_b, fp32
    hipLaunchKernelGGL((gemm256q<0, 0>), dim3(GBLK8), dim3(512), 0, stream,
                       houtb, bwproj, projb, (void*)out, 2 * DD, DD);
}